// Round 9
// baseline (216.825 us; speedup 1.0000x reference)
//
#include <hip/hip_runtime.h>

#define Bc 4
#define Sc 2048
#define Ec 1024
#define Hc 16
#define Dc 64
#define BSc 8192  // B*S
#define KVB 64

typedef short bf16x8 __attribute__((ext_vector_type(8)));
typedef float f32x4 __attribute__((ext_vector_type(4)));
typedef unsigned short u16;
typedef unsigned long long u64;

__device__ __forceinline__ u16 f2bf(float f){
  unsigned u = __builtin_bit_cast(unsigned, f);
  u += 0x7FFFu + ((u >> 16) & 1u);
  return (u16)(u >> 16);
}
__device__ __forceinline__ void gll16(const void* g, void* l){
  __builtin_amdgcn_global_load_lds((const __attribute__((address_space(1))) void*)g,
                                   (__attribute__((address_space(3))) void*)l, 16, 0, 0);
}
// exp2: NO inline asm — builtin (compiler-modeled hazards) or OCML fallback.
__device__ __forceinline__ float exp2_s(float x){
#if __has_builtin(__builtin_amdgcn_exp2f)
  return __builtin_amdgcn_exp2f(x);
#else
  return exp2f(x);
#endif
}

// ---- x fp32 -> bf16 ----
__global__ void cvt_x_kernel(const float* __restrict__ x, u16* __restrict__ xb, int n){
  int i = (blockIdx.x * 256 + threadIdx.x) * 4;
  if (i >= n) return;
  float4 v = *(const float4*)(x + i);
  *(ushort4*)(xb+i) = make_ushort4(f2bf(v.x), f2bf(v.y), f2bf(v.z), f2bf(v.w));
}

// ---- transpose + convert weights: W[k][n] fp32 -> Wt[n][k] bf16 ----
__global__ void wt_kernel(const float* __restrict__ w0, const float* __restrict__ w1,
                          const float* __restrict__ w2, const float* __restrict__ w3,
                          u16* __restrict__ wt){
  const float* w = blockIdx.z==0 ? w0 : blockIdx.z==1 ? w1 : blockIdx.z==2 ? w2 : w3;
  u16* ho = wt + (size_t)blockIdx.z * Ec * Ec;
  __shared__ float t[32][33];
  int k0 = blockIdx.y * 32, n0 = blockIdx.x * 32;
  int tx = threadIdx.x & 31, ty = threadIdx.x >> 5;
  for (int i = 0; i < 4; ++i){
    int k = ty + i*8;
    t[k][tx] = w[(size_t)(k0+k)*Ec + n0 + tx];
  }
  __syncthreads();
  for (int i = 0; i < 4; ++i){
    int nn = ty + i*8;
    ho[(size_t)(n0+nn)*Ec + k0 + tx] = f2bf(t[tx][nn]);
  }
}

// ---- fused QKV GEMM: C[M][3072] = A[M][K] @ [Wq;Wk;Wv]^T, m97 structure ----
// which = n block / 1024: 0 -> Q [bh][s][d] scaled by 0.125*log2(e)
//                         1 -> K [bh][s][d]
//                         2 -> V^T [bh][d][s]
__global__ __launch_bounds__(256, 2)
void gemm_qkv(const u16* __restrict__ A, const u16* __restrict__ Wt,
              const float* __restrict__ bq, const float* __restrict__ bk,
              const float* __restrict__ bv,
              u16* __restrict__ qout, u16* __restrict__ kout, u16* __restrict__ vout)
{
  constexpr int K = Ec;
  __shared__ alignas(16) u16 As[128*32];
  __shared__ alignas(16) u16 Bs[128*32];
  const int tid = threadIdx.x, lane = tid & 63, w = tid >> 6;
  const int wr = w >> 1, wc = w & 1;
  const int m0 = blockIdx.y * 128;
  const int n0g = blockIdx.x * 128;
  const int which = n0g >> 10;
  const int n0 = n0g & 1023;
  const u16* Bt = Wt + (size_t)which * Ec * Ec;
  const float* bias = which == 0 ? bq : which == 1 ? bk : bv;
  const int l15 = lane & 15, kslot = lane >> 4;
  const f32x4 fz = {0.f,0.f,0.f,0.f};
  f32x4 acc[4][4];
  for (int i=0;i<4;++i) for (int j=0;j<4;++j) acc[i][j] = fz;

  const int srow = lane >> 2, sslot = lane & 3;

  for (int k0 = 0; k0 < K; k0 += 32){
    __syncthreads();
    for (int i = 0; i < 2; ++i){
      int c = w*2 + i;
      int row = c*16 + srow;
      int sw = (row ^ (row >> 2)) & 3;
      gll16(A  + (size_t)(m0+row)*K + k0 + ((sslot ^ sw) << 3), As + c*512);
      gll16(Bt + (size_t)(n0+row)*K + k0 + ((sslot ^ sw) << 3), Bs + c*512);
    }
    __syncthreads();
    bf16x8 af[4], bfr[4];
    for (int mi = 0; mi < 4; ++mi){
      int row = wr*64 + mi*16 + l15;
      int sw = (row ^ (row >> 2)) & 3;
      af[mi] = *(const bf16x8*)(As + row*32 + ((kslot ^ sw) << 3));
    }
    for (int ni = 0; ni < 4; ++ni){
      int row = wc*64 + ni*16 + l15;
      int sw = (row ^ (row >> 2)) & 3;
      bfr[ni] = *(const bf16x8*)(Bs + row*32 + ((kslot ^ sw) << 3));
    }
    for (int mi = 0; mi < 4; ++mi)
      for (int ni = 0; ni < 4; ++ni)
        acc[mi][ni] = __builtin_amdgcn_mfma_f32_16x16x32_bf16(af[mi], bfr[ni], acc[mi][ni], 0, 0, 0);
  }

  for (int mi = 0; mi < 4; ++mi){
    for (int ni = 0; ni < 4; ++ni){
      int col = n0 + wc*64 + ni*16 + l15;           // 0..1023 within this matrix
      int row0 = m0 + wr*64 + mi*16 + kslot*4;
      float bi = bias[col];
      if (which == 2){
        int bb = row0 >> 11, s0 = row0 & 2047;
        int hh = col >> 6, dd = col & 63;
        ushort4 pk = make_ushort4(f2bf(acc[mi][ni][0]+bi), f2bf(acc[mi][ni][1]+bi),
                                  f2bf(acc[mi][ni][2]+bi), f2bf(acc[mi][ni][3]+bi));
        *(ushort4*)(vout + ((size_t)(bb*Hc+hh)*Dc + dd)*Sc + s0) = pk;
      } else {
        u16* dst = which == 0 ? qout : kout;
        for (int j = 0; j < 4; ++j){
          float v = acc[mi][ni][j] + bi;
          int row = row0 + j;
          float vv = (which == 0) ? v * 0.18033688f : v;   // 0.125 * log2(e)
          int bb = row >> 11, ss = row & 2047;
          int hh = col >> 6, dd = col & 63;
          dst[((size_t)(bb*Hc+hh)*Sc + ss)*Dc + dd] = f2bf(vv);
        }
      }
    }
  }
}

// ---- output projection GEMM: fp32 out ----
__global__ __launch_bounds__(256, 2)
void gemm_out(const u16* __restrict__ A, const u16* __restrict__ Bt,
              const float* __restrict__ bias, float* __restrict__ outp)
{
  constexpr int K = Ec;
  __shared__ alignas(16) u16 As[128*32];
  __shared__ alignas(16) u16 Bs[128*32];
  const int tid = threadIdx.x, lane = tid & 63, w = tid >> 6;
  const int wr = w >> 1, wc = w & 1;
  const int m0 = blockIdx.y * 128, n0 = blockIdx.x * 128;
  const int l15 = lane & 15, kslot = lane >> 4;
  const f32x4 fz = {0.f,0.f,0.f,0.f};
  f32x4 acc[4][4];
  for (int i=0;i<4;++i) for (int j=0;j<4;++j) acc[i][j] = fz;

  const int srow = lane >> 2, sslot = lane & 3;

  for (int k0 = 0; k0 < K; k0 += 32){
    __syncthreads();
    for (int i = 0; i < 2; ++i){
      int c = w*2 + i;
      int row = c*16 + srow;
      int sw = (row ^ (row >> 2)) & 3;
      gll16(A  + (size_t)(m0+row)*K + k0 + ((sslot ^ sw) << 3), As + c*512);
      gll16(Bt + (size_t)(n0+row)*K + k0 + ((sslot ^ sw) << 3), Bs + c*512);
    }
    __syncthreads();
    bf16x8 af[4], bfr[4];
    for (int mi = 0; mi < 4; ++mi){
      int row = wr*64 + mi*16 + l15;
      int sw = (row ^ (row >> 2)) & 3;
      af[mi] = *(const bf16x8*)(As + row*32 + ((kslot ^ sw) << 3));
    }
    for (int ni = 0; ni < 4; ++ni){
      int row = wc*64 + ni*16 + l15;
      int sw = (row ^ (row >> 2)) & 3;
      bfr[ni] = *(const bf16x8*)(Bs + row*32 + ((kslot ^ sw) << 3));
    }
    for (int mi = 0; mi < 4; ++mi)
      for (int ni = 0; ni < 4; ++ni)
        acc[mi][ni] = __builtin_amdgcn_mfma_f32_16x16x32_bf16(af[mi], bfr[ni], acc[mi][ni], 0, 0, 0);
  }

  for (int mi = 0; mi < 4; ++mi){
    for (int ni = 0; ni < 4; ++ni){
      int col = n0 + wc*64 + ni*16 + l15;
      int row0 = m0 + wr*64 + mi*16 + kslot*4;
      float bi = bias[col];
      for (int j = 0; j < 4; ++j)
        outp[(size_t)(row0+j)*Ec + col] = acc[mi][ni][j] + bi;
    }
  }
}

// ---- flash attention: 4 waves x 64 q-rows, KV tiles of 64, dbuf staging,
//      swapped QK^T (round-6-proven softmax), P in registers (pi-permuted PV),
//      mask hoisted, defer-max. ZERO value-producing inline asm. ----
__global__ __launch_bounds__(256, 2)
void attn_kernel(const u16* __restrict__ qb, const u16* __restrict__ kb,
                 const u16* __restrict__ vt, const int* __restrict__ mask,
                 u16* __restrict__ ob)
{
  __shared__ alignas(16) u16 Ks[2][KVB*Dc];   // [t][d] 128B rows, slot-swizzled
  __shared__ alignas(16) u16 Vs[2][Dc*KVB];   // [d][t] 128B rows, slot-swizzled
  const int tid = threadIdx.x, lane = tid & 63, w = tid >> 6;
  const int l15 = lane & 15, ks = lane >> 4;
  // XCD-affinity remap: 512 blocks -> xcd*64 + orig/8 (bijective)
  const int wg = ((blockIdx.x & 7) << 6) | (blockIdx.x >> 3);
  const int bh = wg >> 3, qblk = wg & 7;
  const int b = bh >> 4, h = bh & 15;
  const int q0 = qblk*256 + w*64;

  const u16* Q  = qb + (size_t)bh*Sc*Dc;
  const u16* Kg = kb + (size_t)bh*Sc*Dc;
  const u16* Vg = vt + (size_t)bh*Dc*Sc;
  const int* mpb = mask + b*Sc;

  // prologue mask scan: allvalid => zero mask work in the hot loop
  int nzl = 1;
  {
    const int4* mv4 = (const int4*)mpb;
#pragma unroll
    for (int i = 0; i < 8; ++i){
      int4 v = mv4[i*64 + lane];
      nzl &= (v.x && v.y && v.z && v.w) ? 1 : 0;
    }
  }
  const bool allvalid = __all(nzl);

  // staging offsets (pre-swizzled global source, linear LDS dest)
  int koff[2], voff[2];
#pragma unroll
  for (int i = 0; i < 2; ++i){
    int S = (w*2+i)*64 + lane;
    int row = S >> 3, s = S & 7;
    koff[i] = row*Dc + ((s ^ (row & 7)) << 3);
    voff[i] = row*Sc + ((s ^ (row & 7)) << 3);
  }
  const int Xl = (l15 & 7) << 4;

  // Q fragments (B-operand: col=l15 -> q, k=ks*8+j -> d)
  bf16x8 qf[4][2];
#pragma unroll
  for (int qa = 0; qa < 4; ++qa)
#pragma unroll
    for (int kd = 0; kd < 2; ++kd)
      qf[qa][kd] = *(const bf16x8*)(Q + (size_t)(q0 + qa*16 + l15)*Dc + kd*32 + ks*8);

  bf16x8 onesb;
#pragma unroll
  for (int j = 0; j < 8; ++j) onesb[j] = (short)0x3F80;  // bf16 1.0

  const f32x4 fz = {0.f,0.f,0.f,0.f};
  f32x4 o[4][4];
#pragma unroll
  for (int qa = 0; qa < 4; ++qa)
#pragma unroll
    for (int db = 0; db < 4; ++db) o[qa][db] = fz;
  float m[4] = {-3e38f,-3e38f,-3e38f,-3e38f}, runl[4] = {0.f,0.f,0.f,0.f};

  // prologue: stage tile 0 -> buf 0
#pragma unroll
  for (int i = 0; i < 2; ++i){
    gll16(Kg + koff[i], &Ks[0][(w*2+i)*512]);
    gll16(Vg + voff[i], &Vs[0][(w*2+i)*512]);
  }

  const int NT = Sc / KVB;
  int cur = 0;
  for (int t = 0; t < NT; ++t){
    asm volatile("s_waitcnt vmcnt(0)" ::: "memory");  // DMA landed
    __syncthreads();                                  // buf[cur] ready for all waves
    if (t + 1 < NT){                       // prefetch next tile into buf^1
      const u16* kg = Kg + (size_t)(t+1)*(KVB*Dc);
      const u16* vg = Vg + (size_t)(t+1)*KVB;
#pragma unroll
      for (int i = 0; i < 2; ++i){
        gll16(kg + koff[i], &Ks[cur^1][(w*2+i)*512]);
        gll16(vg + voff[i], &Vs[cur^1][(w*2+i)*512]);
      }
    }
    const char* Ksb = (const char*)&Ks[cur][0];
    const char* Vsb = (const char*)&Vs[cur][0];

    // S^T = K @ Q^T : lane holds kv = nb*16 + ks*4 + r, q = qa*16 + l15
    f32x4 sc[4][4];
#pragma unroll
    for (int nb = 0; nb < 4; ++nb){
      bf16x8 kf0 = *(const bf16x8*)(Ksb + nb*2048 + l15*128 + (((0*4+ks) << 4) ^ Xl));
      bf16x8 kf1 = *(const bf16x8*)(Ksb + nb*2048 + l15*128 + (((1*4+ks) << 4) ^ Xl));
#pragma unroll
      for (int qa = 0; qa < 4; ++qa){
        sc[nb][qa] = __builtin_amdgcn_mfma_f32_16x16x32_bf16(kf0, qf[qa][0], fz, 0,0,0);
        sc[nb][qa] = __builtin_amdgcn_mfma_f32_16x16x32_bf16(kf1, qf[qa][1], sc[nb][qa], 0,0,0);
      }
    }
    // key-padding mask (cold for all-valid mask; per-tile scalar loads otherwise)
    if (!allvalid){
      const int* mp = mpb + t*KVB;
#pragma unroll
      for (int nb = 0; nb < 4; ++nb)
#pragma unroll
        for (int r = 0; r < 4; ++r){
          float bi = mp[nb*16 + ks*4 + r] ? 0.f : -3e38f;
#pragma unroll
          for (int qa = 0; qa < 4; ++qa) sc[nb][qa][r] += bi;
        }
    }
    // in-lane partial max per qa (no cross-lane in the hot path)
    float pmax[4];
#pragma unroll
    for (int qa = 0; qa < 4; ++qa){
      f32x4 mx4;
#pragma unroll
      for (int r = 0; r < 4; ++r)
        mx4[r] = fmaxf(fmaxf(sc[0][qa][r], sc[1][qa][r]),
                       fmaxf(sc[2][qa][r], sc[3][qa][r]));
      pmax[qa] = fmaxf(fmaxf(mx4[0], mx4[1]), fmaxf(mx4[2], mx4[3]));
    }
    // defer-max: rescale only if some lane's partial max exceeds m+8 (log2 dom.)
    int ok = (t > 0) && (pmax[0] <= m[0] + 8.f) && (pmax[1] <= m[1] + 8.f)
                     && (pmax[2] <= m[2] + 8.f) && (pmax[3] <= m[3] + 8.f);
    if (!__all(ok)){
#pragma unroll
      for (int qa = 0; qa < 4; ++qa){
        float tv = pmax[qa];
        tv = fmaxf(tv, __shfl_xor(tv, 16, 64));
        tv = fmaxf(tv, __shfl_xor(tv, 32, 64));
        float nm = fmaxf(m[qa], tv);
        float al = exp2_s(m[qa] - nm);
        m[qa] = nm;
        runl[qa] *= al;
#pragma unroll
        for (int db = 0; db < 4; ++db)
#pragma unroll
          for (int r = 0; r < 4; ++r)
            o[qa][db][r] *= al;
      }
    }
    // P = exp2(S - m) in place
#pragma unroll
    for (int nb = 0; nb < 4; ++nb)
#pragma unroll
      for (int qa = 0; qa < 4; ++qa)
#pragma unroll
        for (int r = 0; r < 4; ++r)
          sc[nb][qa][r] = exp2_s(sc[nb][qa][r] - m[qa]);

    // PV: pi(kt,ks,j) = kt*32 + 16*(j>>2) + ks*4 + (j&3) on BOTH operands.
    // P packed with pure-C f2bf (no inline asm); V fragment = two u64 LDS reads.
    f32x4 accl[4] = {fz, fz, fz, fz};
#pragma unroll
    for (int kt = 0; kt < 2; ++kt){
      bf16x8 pb[4];
#pragma unroll
      for (int qa = 0; qa < 4; ++qa){
        bf16x8 tb;
#pragma unroll
        for (int r = 0; r < 4; ++r){
          tb[r]     = (short)f2bf(sc[2*kt  ][qa][r]);
          tb[4 + r] = (short)f2bf(sc[2*kt+1][qa][r]);
        }
        pb[qa] = tb;
        accl[qa] = __builtin_amdgcn_mfma_f32_16x16x32_bf16(onesb, pb[qa], accl[qa], 0,0,0);
      }
#pragma unroll
      for (int db = 0; db < 4; ++db){
        union { bf16x8 v; u64 q[2]; } vu;
        const int g0 = kt*4 + (ks >> 1);
        const int base = db*2048 + l15*128 + (ks & 1)*8;
        vu.q[0] = *(const u64*)(Vsb + base + (((g0    ) << 4) ^ Xl));
        vu.q[1] = *(const u64*)(Vsb + base + (((g0 + 2) << 4) ^ Xl));
#pragma unroll
        for (int qa = 0; qa < 4; ++qa)
          o[qa][db] = __builtin_amdgcn_mfma_f32_16x16x32_bf16(vu.v, pb[qa], o[qa][db], 0,0,0);
      }
    }
#pragma unroll
    for (int qa = 0; qa < 4; ++qa) runl[qa] += accl[qa][0];
    cur ^= 1;
  }
  // epilogue: O[q][d], q = qa*16+l15 (same layout as runl), d = db*16 + ks*4 + r
#pragma unroll
  for (int qa = 0; qa < 4; ++qa){
    float inv = __builtin_amdgcn_rcpf(fmaxf(runl[qa], 1e-35f));
    u16* orow = ob + ((size_t)(b*Sc + q0 + qa*16 + l15))*Ec + h*Dc + ks*4;
#pragma unroll
    for (int db = 0; db < 4; ++db){
      ushort4 pk = make_ushort4(f2bf(o[qa][db][0]*inv), f2bf(o[qa][db][1]*inv),
                                f2bf(o[qa][db][2]*inv), f2bf(o[qa][db][3]*inv));
      *(ushort4*)(orow + db*16) = pk;
    }
  }
}

extern "C" void kernel_launch(void* const* d_in, const int* in_sizes, int n_in,
                              void* d_out, int out_size, void* d_ws, size_t ws_size,
                              hipStream_t stream) {
  const float* x  = (const float*)d_in[0];
  const int* mask = (const int*)d_in[1];
  const float* Wq = (const float*)d_in[2];
  const float* bq = (const float*)d_in[3];
  const float* Wk = (const float*)d_in[4];
  const float* bk = (const float*)d_in[5];
  const float* Wv = (const float*)d_in[6];
  const float* bv = (const float*)d_in[7];
  const float* Wo = (const float*)d_in[8];
  const float* bo = (const float*)d_in[9];
  float* out = (float*)d_out;

  u16* ws   = (u16*)d_ws;
  u16* x_bf = ws;                          // [b*S+s][e]
  u16* w_t  = x_bf + (size_t)BSc*Ec;       // 4 transposed weight matrices [n][k]
  u16* q_bf = w_t  + (size_t)4*Ec*Ec;      // [bh][s][d], pre-scaled by 0.125*log2e
  u16* k_bf = q_bf + (size_t)BSc*Ec;       // [bh][s][d]
  u16* v_t  = k_bf + (size_t)BSc*Ec;       // [bh][d][s]
  u16* o_bf = v_t  + (size_t)BSc*Ec;       // [b*S+s][e]

  cvt_x_kernel<<<BSc*Ec/1024, 256, 0, stream>>>(x, x_bf, BSc*Ec);
  wt_kernel<<<dim3(32,32,4), 256, 0, stream>>>(Wq, Wk, Wv, Wo, w_t);

  const size_t WSZ = (size_t)Ec*Ec;
  gemm_qkv<<<dim3(24,64), 256, 0, stream>>>(x_bf, w_t, bq, bk, bv, q_bf, k_bf, v_t);

  attn_kernel<<<dim3(512), 256, 0, stream>>>(q_bf, k_bf, v_t, mask, o_bf);

  gemm_out<<<dim3(8,64), 256, 0, stream>>>(o_bf, w_t+3*WSZ, bo, out);
}

// Round 11
// 214.777 us; speedup vs baseline: 1.0095x; 1.0095x over previous
//
#include <hip/hip_runtime.h>
#include <hip/hip_bf16.h>

#define Bc 4
#define Sc 2048
#define Ec 1024
#define Hc 16
#define Dc 64
#define BSc 8192  // B*S
#define KVB 64

typedef short bf16x8 __attribute__((ext_vector_type(8)));
typedef float f32x4 __attribute__((ext_vector_type(4)));
typedef unsigned short u16;
typedef unsigned long long u64;

__device__ __forceinline__ u16 f2bf(float f){
  unsigned u = __builtin_bit_cast(unsigned, f);
  u += 0x7FFFu + ((u >> 16) & 1u);
  return (u16)(u >> 16);
}
__device__ __forceinline__ void gll16(const void* g, void* l){
  __builtin_amdgcn_global_load_lds((const __attribute__((address_space(1))) void*)g,
                                   (__attribute__((address_space(3))) void*)l, 16, 0, 0);
}
// exp2: builtin only (round-9-proven: no value-producing inline asm).
__device__ __forceinline__ float exp2_s(float x){
#if __has_builtin(__builtin_amdgcn_exp2f)
  return __builtin_amdgcn_exp2f(x);
#else
  return exp2f(x);
#endif
}
// packed f32x2 -> bf16x2 via HIP intrinsic (lowers to v_cvt_pk_bf16_f32, no asm).
// __hip_bfloat162 is not trivially copyable -> memcpy instead of bit_cast.
__device__ __forceinline__ unsigned pack2bf(float a, float b){
  __hip_bfloat162 h = __float22bfloat162_rn(make_float2(a, b));
  unsigned r;
  __builtin_memcpy(&r, &h, 4);
  return r;
}

// ---- x fp32 -> bf16 ----
__global__ void cvt_x_kernel(const float* __restrict__ x, u16* __restrict__ xb, int n){
  int i = (blockIdx.x * 256 + threadIdx.x) * 4;
  if (i >= n) return;
  float4 v = *(const float4*)(x + i);
  *(ushort4*)(xb+i) = make_ushort4(f2bf(v.x), f2bf(v.y), f2bf(v.z), f2bf(v.w));
}

// ---- transpose + convert weights: W[k][n] fp32 -> Wt[n][k] bf16 ----
__global__ void wt_kernel(const float* __restrict__ w0, const float* __restrict__ w1,
                          const float* __restrict__ w2, const float* __restrict__ w3,
                          u16* __restrict__ wt){
  const float* w = blockIdx.z==0 ? w0 : blockIdx.z==1 ? w1 : blockIdx.z==2 ? w2 : w3;
  u16* ho = wt + (size_t)blockIdx.z * Ec * Ec;
  __shared__ float t[32][33];
  int k0 = blockIdx.y * 32, n0 = blockIdx.x * 32;
  int tx = threadIdx.x & 31, ty = threadIdx.x >> 5;
  for (int i = 0; i < 4; ++i){
    int k = ty + i*8;
    t[k][tx] = w[(size_t)(k0+k)*Ec + n0 + tx];
  }
  __syncthreads();
  for (int i = 0; i < 4; ++i){
    int nn = ty + i*8;
    ho[(size_t)(n0+nn)*Ec + k0 + tx] = f2bf(t[tx][nn]);
  }
}

// ---- fused QKV GEMM: C[M][3072] = A[M][K] @ [Wq;Wk;Wv]^T, m97 structure ----
// which = n block / 1024: 0 -> Q [bh][s][d] scaled by 0.125*log2(e)
//                         1 -> K [bh][s][d]
//                         2 -> V^T [bh][d][s]
__global__ __launch_bounds__(256, 2)
void gemm_qkv(const u16* __restrict__ A, const u16* __restrict__ Wt,
              const float* __restrict__ bq, const float* __restrict__ bk,
              const float* __restrict__ bv,
              u16* __restrict__ qout, u16* __restrict__ kout, u16* __restrict__ vout)
{
  constexpr int K = Ec;
  __shared__ alignas(16) u16 As[128*32];
  __shared__ alignas(16) u16 Bs[128*32];
  const int tid = threadIdx.x, lane = tid & 63, w = tid >> 6;
  const int wr = w >> 1, wc = w & 1;
  const int m0 = blockIdx.y * 128;
  const int n0g = blockIdx.x * 128;
  const int which = n0g >> 10;
  const int n0 = n0g & 1023;
  const u16* Bt = Wt + (size_t)which * Ec * Ec;
  const float* bias = which == 0 ? bq : which == 1 ? bk : bv;
  const int l15 = lane & 15, kslot = lane >> 4;
  const f32x4 fz = {0.f,0.f,0.f,0.f};
  f32x4 acc[4][4];
  for (int i=0;i<4;++i) for (int j=0;j<4;++j) acc[i][j] = fz;

  const int srow = lane >> 2, sslot = lane & 3;

  for (int k0 = 0; k0 < K; k0 += 32){
    __syncthreads();
    for (int i = 0; i < 2; ++i){
      int c = w*2 + i;
      int row = c*16 + srow;
      int sw = (row ^ (row >> 2)) & 3;
      gll16(A  + (size_t)(m0+row)*K + k0 + ((sslot ^ sw) << 3), As + c*512);
      gll16(Bt + (size_t)(n0+row)*K + k0 + ((sslot ^ sw) << 3), Bs + c*512);
    }
    __syncthreads();
    bf16x8 af[4], bfr[4];
    for (int mi = 0; mi < 4; ++mi){
      int row = wr*64 + mi*16 + l15;
      int sw = (row ^ (row >> 2)) & 3;
      af[mi] = *(const bf16x8*)(As + row*32 + ((kslot ^ sw) << 3));
    }
    for (int ni = 0; ni < 4; ++ni){
      int row = wc*64 + ni*16 + l15;
      int sw = (row ^ (row >> 2)) & 3;
      bfr[ni] = *(const bf16x8*)(Bs + row*32 + ((kslot ^ sw) << 3));
    }
    for (int mi = 0; mi < 4; ++mi)
      for (int ni = 0; ni < 4; ++ni)
        acc[mi][ni] = __builtin_amdgcn_mfma_f32_16x16x32_bf16(af[mi], bfr[ni], acc[mi][ni], 0, 0, 0);
  }

  for (int mi = 0; mi < 4; ++mi){
    for (int ni = 0; ni < 4; ++ni){
      int col = n0 + wc*64 + ni*16 + l15;           // 0..1023 within this matrix
      int row0 = m0 + wr*64 + mi*16 + kslot*4;
      float bi = bias[col];
      if (which == 2){
        int bb = row0 >> 11, s0 = row0 & 2047;
        int hh = col >> 6, dd = col & 63;
        ushort4 pk = make_ushort4(f2bf(acc[mi][ni][0]+bi), f2bf(acc[mi][ni][1]+bi),
                                  f2bf(acc[mi][ni][2]+bi), f2bf(acc[mi][ni][3]+bi));
        *(ushort4*)(vout + ((size_t)(bb*Hc+hh)*Dc + dd)*Sc + s0) = pk;
      } else {
        u16* dst = which == 0 ? qout : kout;
        for (int j = 0; j < 4; ++j){
          float v = acc[mi][ni][j] + bi;
          int row = row0 + j;
          float vv = (which == 0) ? v * 0.18033688f : v;   // 0.125 * log2(e)
          int bb = row >> 11, ss = row & 2047;
          int hh = col >> 6, dd = col & 63;
          dst[((size_t)(bb*Hc+hh)*Sc + ss)*Dc + dd] = f2bf(vv);
        }
      }
    }
  }
}

// ---- output projection GEMM: fp32 out ----
__global__ __launch_bounds__(256, 2)
void gemm_out(const u16* __restrict__ A, const u16* __restrict__ Bt,
              const float* __restrict__ bias, float* __restrict__ outp)
{
  constexpr int K = Ec;
  __shared__ alignas(16) u16 As[128*32];
  __shared__ alignas(16) u16 Bs[128*32];
  const int tid = threadIdx.x, lane = tid & 63, w = tid >> 6;
  const int wr = w >> 1, wc = w & 1;
  const int m0 = blockIdx.y * 128, n0 = blockIdx.x * 128;
  const int l15 = lane & 15, kslot = lane >> 4;
  const f32x4 fz = {0.f,0.f,0.f,0.f};
  f32x4 acc[4][4];
  for (int i=0;i<4;++i) for (int j=0;j<4;++j) acc[i][j] = fz;

  const int srow = lane >> 2, sslot = lane & 3;

  for (int k0 = 0; k0 < K; k0 += 32){
    __syncthreads();
    for (int i = 0; i < 2; ++i){
      int c = w*2 + i;
      int row = c*16 + srow;
      int sw = (row ^ (row >> 2)) & 3;
      gll16(A  + (size_t)(m0+row)*K + k0 + ((sslot ^ sw) << 3), As + c*512);
      gll16(Bt + (size_t)(n0+row)*K + k0 + ((sslot ^ sw) << 3), Bs + c*512);
    }
    __syncthreads();
    bf16x8 af[4], bfr[4];
    for (int mi = 0; mi < 4; ++mi){
      int row = wr*64 + mi*16 + l15;
      int sw = (row ^ (row >> 2)) & 3;
      af[mi] = *(const bf16x8*)(As + row*32 + ((kslot ^ sw) << 3));
    }
    for (int ni = 0; ni < 4; ++ni){
      int row = wc*64 + ni*16 + l15;
      int sw = (row ^ (row >> 2)) & 3;
      bfr[ni] = *(const bf16x8*)(Bs + row*32 + ((kslot ^ sw) << 3));
    }
    for (int mi = 0; mi < 4; ++mi)
      for (int ni = 0; ni < 4; ++ni)
        acc[mi][ni] = __builtin_amdgcn_mfma_f32_16x16x32_bf16(af[mi], bfr[ni], acc[mi][ni], 0, 0, 0);
  }

  for (int mi = 0; mi < 4; ++mi){
    for (int ni = 0; ni < 4; ++ni){
      int col = n0 + wc*64 + ni*16 + l15;
      int row0 = m0 + wr*64 + mi*16 + kslot*4;
      float bi = bias[col];
      for (int j = 0; j < 4; ++j)
        outp[(size_t)(row0+j)*Ec + col] = acc[mi][ni][j] + bi;
    }
  }
}

// ---- flash attention: round-6-proven 32q structure. 4 waves x 32 q-rows,
//      KV tiles of 64, dbuf staging, swapped QK^T, P in registers (pi-permuted
//      PV, two-u64 V read), mask hoisted, defer-max. Safe additions only:
//      builtin exp2, intrinsic cvt_pk pack, setprio around MFMA clusters. ----
__global__ __launch_bounds__(256, 2)
void attn_kernel(const u16* __restrict__ qb, const u16* __restrict__ kb,
                 const u16* __restrict__ vt, const int* __restrict__ mask,
                 u16* __restrict__ ob)
{
  __shared__ alignas(16) u16 Ks[2][KVB*Dc];   // [t][d] 128B rows, slot-swizzled
  __shared__ alignas(16) u16 Vs[2][Dc*KVB];   // [d][t] 128B rows, slot-swizzled
  const int tid = threadIdx.x, lane = tid & 63, w = tid >> 6;
  const int l15 = lane & 15, ks = lane >> 4;
  // XCD-affinity remap: 1024 blocks -> xcd*128 + orig/8 (bijective)
  const int wg = ((blockIdx.x & 7) << 7) | (blockIdx.x >> 3);
  const int bh = wg >> 4, qblk = wg & 15;
  const int b = bh >> 4, h = bh & 15;
  const int q0 = qblk*128 + w*32;

  const u16* Q  = qb + (size_t)bh*Sc*Dc;
  const u16* Kg = kb + (size_t)bh*Sc*Dc;
  const u16* Vg = vt + (size_t)bh*Dc*Sc;
  const int* mpb = mask + b*Sc;

  // prologue mask scan: allvalid => zero mask work in the hot loop
  int nzl = 1;
  {
    const int4* mv4 = (const int4*)mpb;
#pragma unroll
    for (int i = 0; i < 8; ++i){
      int4 v = mv4[i*64 + lane];
      nzl &= (v.x && v.y && v.z && v.w) ? 1 : 0;
    }
  }
  const bool allvalid = __all(nzl);

  // staging offsets (pre-swizzled global source, linear LDS dest)
  int koff[2], voff[2];
#pragma unroll
  for (int i = 0; i < 2; ++i){
    int S = (w*2+i)*64 + lane;
    int row = S >> 3, s = S & 7;
    koff[i] = row*Dc + ((s ^ (row & 7)) << 3);
    voff[i] = row*Sc + ((s ^ (row & 7)) << 3);
  }
  const int Xl = (l15 & 7) << 4;

  // Q fragments (B-operand: col=l15 -> q, k=ks*8+j -> d)
  bf16x8 qf[2][2];
#pragma unroll
  for (int qa = 0; qa < 2; ++qa)
#pragma unroll
    for (int kd = 0; kd < 2; ++kd)
      qf[qa][kd] = *(const bf16x8*)(Q + (size_t)(q0 + qa*16 + l15)*Dc + kd*32 + ks*8);

  bf16x8 onesb;
#pragma unroll
  for (int j = 0; j < 8; ++j) onesb[j] = (short)0x3F80;  // bf16 1.0

  const f32x4 fz = {0.f,0.f,0.f,0.f};
  f32x4 o[2][4];
#pragma unroll
  for (int qa = 0; qa < 2; ++qa)
#pragma unroll
    for (int db = 0; db < 4; ++db) o[qa][db] = fz;
  float m[2] = {-3e38f, -3e38f}, runl[2] = {0.f, 0.f};

  // prologue: stage tile 0 -> buf 0
#pragma unroll
  for (int i = 0; i < 2; ++i){
    gll16(Kg + koff[i], &Ks[0][(w*2+i)*512]);
    gll16(Vg + voff[i], &Vs[0][(w*2+i)*512]);
  }

  const int NT = Sc / KVB;
  int cur = 0;
  for (int t = 0; t < NT; ++t){
    asm volatile("s_waitcnt vmcnt(0)" ::: "memory");  // DMA landed
    __syncthreads();                                  // buf[cur] ready for all waves
    if (t + 1 < NT){                       // prefetch next tile into buf^1
      const u16* kg = Kg + (size_t)(t+1)*(KVB*Dc);
      const u16* vg = Vg + (size_t)(t+1)*KVB;
#pragma unroll
      for (int i = 0; i < 2; ++i){
        gll16(kg + koff[i], &Ks[cur^1][(w*2+i)*512]);
        gll16(vg + voff[i], &Vs[cur^1][(w*2+i)*512]);
      }
    }
    const char* Ksb = (const char*)&Ks[cur][0];
    const char* Vsb = (const char*)&Vs[cur][0];

    // S^T = K @ Q^T : lane holds kv = nb*16 + ks*4 + r, q = qa*16 + l15
    f32x4 sc[4][2];
    __builtin_amdgcn_s_setprio(1);
#pragma unroll
    for (int nb = 0; nb < 4; ++nb){
      bf16x8 kf0 = *(const bf16x8*)(Ksb + nb*2048 + l15*128 + (((0*4+ks) << 4) ^ Xl));
      bf16x8 kf1 = *(const bf16x8*)(Ksb + nb*2048 + l15*128 + (((1*4+ks) << 4) ^ Xl));
#pragma unroll
      for (int qa = 0; qa < 2; ++qa){
        sc[nb][qa] = __builtin_amdgcn_mfma_f32_16x16x32_bf16(kf0, qf[qa][0], fz, 0,0,0);
        sc[nb][qa] = __builtin_amdgcn_mfma_f32_16x16x32_bf16(kf1, qf[qa][1], sc[nb][qa], 0,0,0);
      }
    }
    __builtin_amdgcn_s_setprio(0);
    // key-padding mask (cold for all-valid mask; per-tile scalar loads otherwise)
    if (!allvalid){
      const int* mp = mpb + t*KVB;
#pragma unroll
      for (int nb = 0; nb < 4; ++nb)
#pragma unroll
        for (int r = 0; r < 4; ++r){
          float bi = mp[nb*16 + ks*4 + r] ? 0.f : -3e38f;
          sc[nb][0][r] += bi;
          sc[nb][1][r] += bi;
        }
    }
    // in-lane partial max per qa (no cross-lane in the hot path)
    float pmax[2];
#pragma unroll
    for (int qa = 0; qa < 2; ++qa){
      f32x4 mx4;
#pragma unroll
      for (int r = 0; r < 4; ++r)
        mx4[r] = fmaxf(fmaxf(sc[0][qa][r], sc[1][qa][r]),
                       fmaxf(sc[2][qa][r], sc[3][qa][r]));
      pmax[qa] = fmaxf(fmaxf(mx4[0], mx4[1]), fmaxf(mx4[2], mx4[3]));
    }
    // defer-max: rescale only if some lane's partial max exceeds m+8 (log2 dom.)
    int ok = (t > 0) && (pmax[0] <= m[0] + 8.f) && (pmax[1] <= m[1] + 8.f);
    if (!__all(ok)){
#pragma unroll
      for (int qa = 0; qa < 2; ++qa){
        float tv = pmax[qa];
        tv = fmaxf(tv, __shfl_xor(tv, 16, 64));
        tv = fmaxf(tv, __shfl_xor(tv, 32, 64));
        float nm = fmaxf(m[qa], tv);
        float al = exp2_s(m[qa] - nm);
        m[qa] = nm;
        runl[qa] *= al;
#pragma unroll
        for (int db = 0; db < 4; ++db)
#pragma unroll
          for (int r = 0; r < 4; ++r)
            o[qa][db][r] *= al;
      }
    }
    // P = exp2(S - m) in place
#pragma unroll
    for (int nb = 0; nb < 4; ++nb)
#pragma unroll
      for (int qa = 0; qa < 2; ++qa)
#pragma unroll
        for (int r = 0; r < 4; ++r)
          sc[nb][qa][r] = exp2_s(sc[nb][qa][r] - m[qa]);

    // PV: pi(kt,ks,j) = kt*32 + 16*(j>>2) + ks*4 + (j&3) on BOTH operands.
    // P packed via cvt_pk intrinsic; V fragment assembled from two u64 LDS reads.
    f32x4 accl[2] = {fz, fz};
#pragma unroll
    for (int kt = 0; kt < 2; ++kt){
      bf16x8 pb[2];
#pragma unroll
      for (int qa = 0; qa < 2; ++qa){
        union { bf16x8 v; unsigned u[4]; } pu;
        pu.u[0] = pack2bf(sc[2*kt  ][qa][0], sc[2*kt  ][qa][1]);
        pu.u[1] = pack2bf(sc[2*kt  ][qa][2], sc[2*kt  ][qa][3]);
        pu.u[2] = pack2bf(sc[2*kt+1][qa][0], sc[2*kt+1][qa][1]);
        pu.u[3] = pack2bf(sc[2*kt+1][qa][2], sc[2*kt+1][qa][3]);
        pb[qa] = pu.v;
      }
      __builtin_amdgcn_s_setprio(1);
      accl[0] = __builtin_amdgcn_mfma_f32_16x16x32_bf16(onesb, pb[0], accl[0], 0,0,0);
      accl[1] = __builtin_amdgcn_mfma_f32_16x16x32_bf16(onesb, pb[1], accl[1], 0,0,0);
#pragma unroll
      for (int db = 0; db < 4; ++db){
        union { bf16x8 v; u64 q[2]; } vu;
        const int g0 = kt*4 + (ks >> 1);
        const int base = db*2048 + l15*128 + (ks & 1)*8;
        vu.q[0] = *(const u64*)(Vsb + base + (((g0    ) << 4) ^ Xl));
        vu.q[1] = *(const u64*)(Vsb + base + (((g0 + 2) << 4) ^ Xl));
#pragma unroll
        for (int qa = 0; qa < 2; ++qa)
          o[qa][db] = __builtin_amdgcn_mfma_f32_16x16x32_bf16(vu.v, pb[qa], o[qa][db], 0,0,0);
      }
      __builtin_amdgcn_s_setprio(0);
    }
    runl[0] += accl[0][0];
    runl[1] += accl[1][0];
    cur ^= 1;
  }
  // epilogue: O[q][d], q = qa*16+l15 (same layout as runl), d = db*16 + ks*4 + r
#pragma unroll
  for (int qa = 0; qa < 2; ++qa){
    float inv = __builtin_amdgcn_rcpf(fmaxf(runl[qa], 1e-35f));
    u16* orow = ob + ((size_t)(b*Sc + q0 + qa*16 + l15))*Ec + h*Dc + ks*4;
#pragma unroll
    for (int db = 0; db < 4; ++db){
      ushort4 pk = make_ushort4(f2bf(o[qa][db][0]*inv), f2bf(o[qa][db][1]*inv),
                                f2bf(o[qa][db][2]*inv), f2bf(o[qa][db][3]*inv));
      *(ushort4*)(orow + db*16) = pk;
    }
  }
}

extern "C" void kernel_launch(void* const* d_in, const int* in_sizes, int n_in,
                              void* d_out, int out_size, void* d_ws, size_t ws_size,
                              hipStream_t stream) {
  const float* x  = (const float*)d_in[0];
  const int* mask = (const int*)d_in[1];
  const float* Wq = (const float*)d_in[2];
  const float* bq = (const float*)d_in[3];
  const float* Wk = (const float*)d_in[4];
  const float* bk = (const float*)d_in[5];
  const float* Wv = (const float*)d_in[6];
  const float* bv = (const float*)d_in[7];
  const float* Wo = (const float*)d_in[8];
  const float* bo = (const float*)d_in[9];
  float* out = (float*)d_out;

  u16* ws   = (u16*)d_ws;
  u16* x_bf = ws;                          // [b*S+s][e]
  u16* w_t  = x_bf + (size_t)BSc*Ec;       // 4 transposed weight matrices [n][k]
  u16* q_bf = w_t  + (size_t)4*Ec*Ec;      // [bh][s][d], pre-scaled by 0.125*log2e
  u16* k_bf = q_bf + (size_t)BSc*Ec;       // [bh][s][d]
  u16* v_t  = k_bf + (size_t)BSc*Ec;       // [bh][d][s]
  u16* o_bf = v_t  + (size_t)BSc*Ec;       // [b*S+s][e]

  cvt_x_kernel<<<BSc*Ec/1024, 256, 0, stream>>>(x, x_bf, BSc*Ec);
  wt_kernel<<<dim3(32,32,4), 256, 0, stream>>>(Wq, Wk, Wv, Wo, w_t);

  const size_t WSZ = (size_t)Ec*Ec;
  gemm_qkv<<<dim3(24,64), 256, 0, stream>>>(x_bf, w_t, bq, bk, bv, q_bf, k_bf, v_t);

  attn_kernel<<<dim3(1024), 256, 0, stream>>>(q_bf, k_bf, v_t, mask, o_bf);

  gemm_out<<<dim3(8,64), 256, 0, stream>>>(o_bf, w_t+3*WSZ, bo, out);
}

// Round 12
// 204.722 us; speedup vs baseline: 1.0591x; 1.0491x over previous
//
#include <hip/hip_runtime.h>

#define Bc 4
#define Sc 2048
#define Ec 1024
#define Hc 16
#define Dc 64
#define BSc 8192  // B*S
#define KVB 64

typedef short bf16x8 __attribute__((ext_vector_type(8)));
typedef float f32x4 __attribute__((ext_vector_type(4)));
typedef unsigned short u16;
typedef unsigned long long u64;

__device__ __forceinline__ u16 f2bf(float f){
  unsigned u = __builtin_bit_cast(unsigned, f);
  u += 0x7FFFu + ((u >> 16) & 1u);
  return (u16)(u >> 16);
}
__device__ __forceinline__ void gll16(const void* g, void* l){
  __builtin_amdgcn_global_load_lds((const __attribute__((address_space(1))) void*)g,
                                   (__attribute__((address_space(3))) void*)l, 16, 0, 0);
}
// exp2: builtin (proven rounds 9/11; compiler-modeled TRANS hazards, no s_nop tax)
__device__ __forceinline__ float exp2_s(float x){
#if __has_builtin(__builtin_amdgcn_exp2f)
  return __builtin_amdgcn_exp2f(x);
#else
  return exp2f(x);
#endif
}
// cvt_pk pack: round-6-proven asm form (passed twice at 32q); 1 inst / 2 elems.
__device__ __forceinline__ unsigned cvtpk(float a, float b){
  unsigned r;
  asm volatile("v_cvt_pk_bf16_f32 %0, %1, %2\n\ts_nop 1" : "=v"(r) : "v"(a), "v"(b));
  return r;
}

// ---- x fp32 -> bf16 ----
__global__ void cvt_x_kernel(const float* __restrict__ x, u16* __restrict__ xb, int n){
  int i = (blockIdx.x * 256 + threadIdx.x) * 4;
  if (i >= n) return;
  float4 v = *(const float4*)(x + i);
  *(ushort4*)(xb+i) = make_ushort4(f2bf(v.x), f2bf(v.y), f2bf(v.z), f2bf(v.w));
}

// ---- transpose + convert weights: W[k][n] fp32 -> Wt[n][k] bf16 ----
__global__ void wt_kernel(const float* __restrict__ w0, const float* __restrict__ w1,
                          const float* __restrict__ w2, const float* __restrict__ w3,
                          u16* __restrict__ wt){
  const float* w = blockIdx.z==0 ? w0 : blockIdx.z==1 ? w1 : blockIdx.z==2 ? w2 : w3;
  u16* ho = wt + (size_t)blockIdx.z * Ec * Ec;
  __shared__ float t[32][33];
  int k0 = blockIdx.y * 32, n0 = blockIdx.x * 32;
  int tx = threadIdx.x & 31, ty = threadIdx.x >> 5;
  for (int i = 0; i < 4; ++i){
    int k = ty + i*8;
    t[k][tx] = w[(size_t)(k0+k)*Ec + n0 + tx];
  }
  __syncthreads();
  for (int i = 0; i < 4; ++i){
    int nn = ty + i*8;
    ho[(size_t)(n0+nn)*Ec + k0 + tx] = f2bf(t[tx][nn]);
  }
}

// ---- fused QKV GEMM: C[M][3072] = A[M][K] @ [Wq;Wk;Wv]^T, m97 structure ----
// which = n block / 1024: 0 -> Q [bh][s][d] scaled by 0.125*log2(e)
//                         1 -> K [bh][s][d]
//                         2 -> V^T [bh][d][s]
__global__ __launch_bounds__(256, 2)
void gemm_qkv(const u16* __restrict__ A, const u16* __restrict__ Wt,
              const float* __restrict__ bq, const float* __restrict__ bk,
              const float* __restrict__ bv,
              u16* __restrict__ qout, u16* __restrict__ kout, u16* __restrict__ vout)
{
  constexpr int K = Ec;
  __shared__ alignas(16) u16 As[128*32];
  __shared__ alignas(16) u16 Bs[128*32];
  const int tid = threadIdx.x, lane = tid & 63, w = tid >> 6;
  const int wr = w >> 1, wc = w & 1;
  const int m0 = blockIdx.y * 128;
  const int n0g = blockIdx.x * 128;
  const int which = n0g >> 10;
  const int n0 = n0g & 1023;
  const u16* Bt = Wt + (size_t)which * Ec * Ec;
  const float* bias = which == 0 ? bq : which == 1 ? bk : bv;
  const int l15 = lane & 15, kslot = lane >> 4;
  const f32x4 fz = {0.f,0.f,0.f,0.f};
  f32x4 acc[4][4];
  for (int i=0;i<4;++i) for (int j=0;j<4;++j) acc[i][j] = fz;

  const int srow = lane >> 2, sslot = lane & 3;

  for (int k0 = 0; k0 < K; k0 += 32){
    __syncthreads();
    for (int i = 0; i < 2; ++i){
      int c = w*2 + i;
      int row = c*16 + srow;
      int sw = (row ^ (row >> 2)) & 3;
      gll16(A  + (size_t)(m0+row)*K + k0 + ((sslot ^ sw) << 3), As + c*512);
      gll16(Bt + (size_t)(n0+row)*K + k0 + ((sslot ^ sw) << 3), Bs + c*512);
    }
    __syncthreads();
    bf16x8 af[4], bfr[4];
    for (int mi = 0; mi < 4; ++mi){
      int row = wr*64 + mi*16 + l15;
      int sw = (row ^ (row >> 2)) & 3;
      af[mi] = *(const bf16x8*)(As + row*32 + ((kslot ^ sw) << 3));
    }
    for (int ni = 0; ni < 4; ++ni){
      int row = wc*64 + ni*16 + l15;
      int sw = (row ^ (row >> 2)) & 3;
      bfr[ni] = *(const bf16x8*)(Bs + row*32 + ((kslot ^ sw) << 3));
    }
    for (int mi = 0; mi < 4; ++mi)
      for (int ni = 0; ni < 4; ++ni)
        acc[mi][ni] = __builtin_amdgcn_mfma_f32_16x16x32_bf16(af[mi], bfr[ni], acc[mi][ni], 0, 0, 0);
  }

  for (int mi = 0; mi < 4; ++mi){
    for (int ni = 0; ni < 4; ++ni){
      int col = n0 + wc*64 + ni*16 + l15;           // 0..1023 within this matrix
      int row0 = m0 + wr*64 + mi*16 + kslot*4;
      float bi = bias[col];
      if (which == 2){
        int bb = row0 >> 11, s0 = row0 & 2047;
        int hh = col >> 6, dd = col & 63;
        ushort4 pk = make_ushort4(f2bf(acc[mi][ni][0]+bi), f2bf(acc[mi][ni][1]+bi),
                                  f2bf(acc[mi][ni][2]+bi), f2bf(acc[mi][ni][3]+bi));
        *(ushort4*)(vout + ((size_t)(bb*Hc+hh)*Dc + dd)*Sc + s0) = pk;
      } else {
        u16* dst = which == 0 ? qout : kout;
        for (int j = 0; j < 4; ++j){
          float v = acc[mi][ni][j] + bi;
          int row = row0 + j;
          float vv = (which == 0) ? v * 0.18033688f : v;   // 0.125 * log2(e)
          int bb = row >> 11, ss = row & 2047;
          int hh = col >> 6, dd = col & 63;
          dst[((size_t)(bb*Hc+hh)*Sc + ss)*Dc + dd] = f2bf(vv);
        }
      }
    }
  }
}

// ---- output projection GEMM: fp32 out ----
__global__ __launch_bounds__(256, 2)
void gemm_out(const u16* __restrict__ A, const u16* __restrict__ Bt,
              const float* __restrict__ bias, float* __restrict__ outp)
{
  constexpr int K = Ec;
  __shared__ alignas(16) u16 As[128*32];
  __shared__ alignas(16) u16 Bs[128*32];
  const int tid = threadIdx.x, lane = tid & 63, w = tid >> 6;
  const int wr = w >> 1, wc = w & 1;
  const int m0 = blockIdx.y * 128, n0 = blockIdx.x * 128;
  const int l15 = lane & 15, kslot = lane >> 4;
  const f32x4 fz = {0.f,0.f,0.f,0.f};
  f32x4 acc[4][4];
  for (int i=0;i<4;++i) for (int j=0;j<4;++j) acc[i][j] = fz;

  const int srow = lane >> 2, sslot = lane & 3;

  for (int k0 = 0; k0 < K; k0 += 32){
    __syncthreads();
    for (int i = 0; i < 2; ++i){
      int c = w*2 + i;
      int row = c*16 + srow;
      int sw = (row ^ (row >> 2)) & 3;
      gll16(A  + (size_t)(m0+row)*K + k0 + ((sslot ^ sw) << 3), As + c*512);
      gll16(Bt + (size_t)(n0+row)*K + k0 + ((sslot ^ sw) << 3), Bs + c*512);
    }
    __syncthreads();
    bf16x8 af[4], bfr[4];
    for (int mi = 0; mi < 4; ++mi){
      int row = wr*64 + mi*16 + l15;
      int sw = (row ^ (row >> 2)) & 3;
      af[mi] = *(const bf16x8*)(As + row*32 + ((kslot ^ sw) << 3));
    }
    for (int ni = 0; ni < 4; ++ni){
      int row = wc*64 + ni*16 + l15;
      int sw = (row ^ (row >> 2)) & 3;
      bfr[ni] = *(const bf16x8*)(Bs + row*32 + ((kslot ^ sw) << 3));
    }
    for (int mi = 0; mi < 4; ++mi)
      for (int ni = 0; ni < 4; ++ni)
        acc[mi][ni] = __builtin_amdgcn_mfma_f32_16x16x32_bf16(af[mi], bfr[ni], acc[mi][ni], 0, 0, 0);
  }

  for (int mi = 0; mi < 4; ++mi){
    for (int ni = 0; ni < 4; ++ni){
      int col = n0 + wc*64 + ni*16 + l15;
      int row0 = m0 + wr*64 + mi*16 + kslot*4;
      float bi = bias[col];
      for (int j = 0; j < 4; ++j)
        outp[(size_t)(row0+j)*Ec + col] = acc[mi][ni][j] + bi;
    }
  }
}

// ---- flash attention: round-6-proven 32q structure, verbatim (asm cvtpk pack),
//      with the single proven-safe substitution: builtin exp2 (no s_nop tax).
//      4 waves x 32 q-rows, KV tiles of 64, dbuf staging, swapped QK^T,
//      P in registers (pi-permuted PV, two-u64 V read), mask hoisted, defer-max. ----
__global__ __launch_bounds__(256, 2)
void attn_kernel(const u16* __restrict__ qb, const u16* __restrict__ kb,
                 const u16* __restrict__ vt, const int* __restrict__ mask,
                 u16* __restrict__ ob)
{
  __shared__ alignas(16) u16 Ks[2][KVB*Dc];   // [t][d] 128B rows, slot-swizzled
  __shared__ alignas(16) u16 Vs[2][Dc*KVB];   // [d][t] 128B rows, slot-swizzled
  const int tid = threadIdx.x, lane = tid & 63, w = tid >> 6;
  const int l15 = lane & 15, ks = lane >> 4;
  // XCD-affinity remap: 1024 blocks -> xcd*128 + orig/8 (bijective)
  const int wg = ((blockIdx.x & 7) << 7) | (blockIdx.x >> 3);
  const int bh = wg >> 4, qblk = wg & 15;
  const int b = bh >> 4, h = bh & 15;
  const int q0 = qblk*128 + w*32;

  const u16* Q  = qb + (size_t)bh*Sc*Dc;
  const u16* Kg = kb + (size_t)bh*Sc*Dc;
  const u16* Vg = vt + (size_t)bh*Dc*Sc;
  const int* mpb = mask + b*Sc;

  // prologue mask scan: allvalid => zero mask work in the hot loop
  int nzl = 1;
  {
    const int4* mv4 = (const int4*)mpb;
#pragma unroll
    for (int i = 0; i < 8; ++i){
      int4 v = mv4[i*64 + lane];
      nzl &= (v.x && v.y && v.z && v.w) ? 1 : 0;
    }
  }
  const bool allvalid = __all(nzl);

  // staging offsets (pre-swizzled global source, linear LDS dest)
  int koff[2], voff[2];
#pragma unroll
  for (int i = 0; i < 2; ++i){
    int S = (w*2+i)*64 + lane;
    int row = S >> 3, s = S & 7;
    koff[i] = row*Dc + ((s ^ (row & 7)) << 3);
    voff[i] = row*Sc + ((s ^ (row & 7)) << 3);
  }
  const int Xl = (l15 & 7) << 4;

  // Q fragments (B-operand: col=l15 -> q, k=ks*8+j -> d)
  bf16x8 qf[2][2];
#pragma unroll
  for (int qa = 0; qa < 2; ++qa)
#pragma unroll
    for (int kd = 0; kd < 2; ++kd)
      qf[qa][kd] = *(const bf16x8*)(Q + (size_t)(q0 + qa*16 + l15)*Dc + kd*32 + ks*8);

  bf16x8 onesb;
#pragma unroll
  for (int j = 0; j < 8; ++j) onesb[j] = (short)0x3F80;  // bf16 1.0

  const f32x4 fz = {0.f,0.f,0.f,0.f};
  f32x4 o[2][4];
#pragma unroll
  for (int qa = 0; qa < 2; ++qa)
#pragma unroll
    for (int db = 0; db < 4; ++db) o[qa][db] = fz;
  float m[2] = {-3e38f, -3e38f}, runl[2] = {0.f, 0.f};

  // prologue: stage tile 0 -> buf 0
#pragma unroll
  for (int i = 0; i < 2; ++i){
    gll16(Kg + koff[i], &Ks[0][(w*2+i)*512]);
    gll16(Vg + voff[i], &Vs[0][(w*2+i)*512]);
  }

  const int NT = Sc / KVB;
  int cur = 0;
  for (int t = 0; t < NT; ++t){
    asm volatile("s_waitcnt vmcnt(0)" ::: "memory");  // DMA landed
    __syncthreads();                                  // buf[cur] ready for all waves
    if (t + 1 < NT){                       // prefetch next tile into buf^1
      const u16* kg = Kg + (size_t)(t+1)*(KVB*Dc);
      const u16* vg = Vg + (size_t)(t+1)*KVB;
#pragma unroll
      for (int i = 0; i < 2; ++i){
        gll16(kg + koff[i], &Ks[cur^1][(w*2+i)*512]);
        gll16(vg + voff[i], &Vs[cur^1][(w*2+i)*512]);
      }
    }
    const char* Ksb = (const char*)&Ks[cur][0];
    const char* Vsb = (const char*)&Vs[cur][0];

    // S^T = K @ Q^T : lane holds kv = nb*16 + ks*4 + r, q = qa*16 + l15
    f32x4 sc[4][2];
#pragma unroll
    for (int nb = 0; nb < 4; ++nb){
      bf16x8 kf0 = *(const bf16x8*)(Ksb + nb*2048 + l15*128 + (((0*4+ks) << 4) ^ Xl));
      bf16x8 kf1 = *(const bf16x8*)(Ksb + nb*2048 + l15*128 + (((1*4+ks) << 4) ^ Xl));
#pragma unroll
      for (int qa = 0; qa < 2; ++qa){
        sc[nb][qa] = __builtin_amdgcn_mfma_f32_16x16x32_bf16(kf0, qf[qa][0], fz, 0,0,0);
        sc[nb][qa] = __builtin_amdgcn_mfma_f32_16x16x32_bf16(kf1, qf[qa][1], sc[nb][qa], 0,0,0);
      }
    }
    // key-padding mask (cold for all-valid mask; per-tile scalar loads otherwise)
    if (!allvalid){
      const int* mp = mpb + t*KVB;
#pragma unroll
      for (int nb = 0; nb < 4; ++nb)
#pragma unroll
        for (int r = 0; r < 4; ++r){
          float bi = mp[nb*16 + ks*4 + r] ? 0.f : -3e38f;
          sc[nb][0][r] += bi;
          sc[nb][1][r] += bi;
        }
    }
    // in-lane partial max per qa (no cross-lane in the hot path)
    float pmax[2];
#pragma unroll
    for (int qa = 0; qa < 2; ++qa){
      f32x4 mx4;
#pragma unroll
      for (int r = 0; r < 4; ++r)
        mx4[r] = fmaxf(fmaxf(sc[0][qa][r], sc[1][qa][r]),
                       fmaxf(sc[2][qa][r], sc[3][qa][r]));
      pmax[qa] = fmaxf(fmaxf(mx4[0], mx4[1]), fmaxf(mx4[2], mx4[3]));
    }
    // defer-max: rescale only if some lane's partial max exceeds m+8 (log2 dom.)
    int ok = (t > 0) && (pmax[0] <= m[0] + 8.f) && (pmax[1] <= m[1] + 8.f);
    if (!__all(ok)){
#pragma unroll
      for (int qa = 0; qa < 2; ++qa){
        float tv = pmax[qa];
        tv = fmaxf(tv, __shfl_xor(tv, 16, 64));
        tv = fmaxf(tv, __shfl_xor(tv, 32, 64));
        float nm = fmaxf(m[qa], tv);
        float al = exp2_s(m[qa] - nm);
        m[qa] = nm;
        runl[qa] *= al;
#pragma unroll
        for (int db = 0; db < 4; ++db)
#pragma unroll
          for (int r = 0; r < 4; ++r)
            o[qa][db][r] *= al;
      }
    }
    // P = exp2(S - m) in place
#pragma unroll
    for (int nb = 0; nb < 4; ++nb)
#pragma unroll
      for (int qa = 0; qa < 2; ++qa)
#pragma unroll
        for (int r = 0; r < 4; ++r)
          sc[nb][qa][r] = exp2_s(sc[nb][qa][r] - m[qa]);

    // PV: pi(kt,ks,j) = kt*32 + 16*(j>>2) + ks*4 + (j&3) on BOTH operands.
    // P packed via asm cvt_pk (round-6-proven); V fragment = two u64 LDS reads.
    f32x4 accl[2] = {fz, fz};
#pragma unroll
    for (int kt = 0; kt < 2; ++kt){
      bf16x8 pb[2];
#pragma unroll
      for (int qa = 0; qa < 2; ++qa){
        union { bf16x8 v; unsigned u[4]; } pu;
        pu.u[0] = cvtpk(sc[2*kt  ][qa][0], sc[2*kt  ][qa][1]);
        pu.u[1] = cvtpk(sc[2*kt  ][qa][2], sc[2*kt  ][qa][3]);
        pu.u[2] = cvtpk(sc[2*kt+1][qa][0], sc[2*kt+1][qa][1]);
        pu.u[3] = cvtpk(sc[2*kt+1][qa][2], sc[2*kt+1][qa][3]);
        pb[qa] = pu.v;
      }
      accl[0] = __builtin_amdgcn_mfma_f32_16x16x32_bf16(onesb, pb[0], accl[0], 0,0,0);
      accl[1] = __builtin_amdgcn_mfma_f32_16x16x32_bf16(onesb, pb[1], accl[1], 0,0,0);
#pragma unroll
      for (int db = 0; db < 4; ++db){
        union { bf16x8 v; u64 q[2]; } vu;
        const int g0 = kt*4 + (ks >> 1);
        const int base = db*2048 + l15*128 + (ks & 1)*8;
        vu.q[0] = *(const u64*)(Vsb + base + (((g0    ) << 4) ^ Xl));
        vu.q[1] = *(const u64*)(Vsb + base + (((g0 + 2) << 4) ^ Xl));
#pragma unroll
        for (int qa = 0; qa < 2; ++qa)
          o[qa][db] = __builtin_amdgcn_mfma_f32_16x16x32_bf16(vu.v, pb[qa], o[qa][db], 0,0,0);
      }
    }
    runl[0] += accl[0][0];
    runl[1] += accl[1][0];
    cur ^= 1;
  }
  // epilogue: O[q][d], q = qa*16+l15 (same layout as runl), d = db*16 + ks*4 + r
#pragma unroll
  for (int qa = 0; qa < 2; ++qa){
    float inv = __builtin_amdgcn_rcpf(fmaxf(runl[qa], 1e-35f));
    u16* orow = ob + ((size_t)(b*Sc + q0 + qa*16 + l15))*Ec + h*Dc + ks*4;
#pragma unroll
    for (int db = 0; db < 4; ++db){
      ushort4 pk = make_ushort4(f2bf(o[qa][db][0]*inv), f2bf(o[qa][db][1]*inv),
                                f2bf(o[qa][db][2]*inv), f2bf(o[qa][db][3]*inv));
      *(ushort4*)(orow + db*16) = pk;
    }
  }
}

extern "C" void kernel_launch(void* const* d_in, const int* in_sizes, int n_in,
                              void* d_out, int out_size, void* d_ws, size_t ws_size,
                              hipStream_t stream) {
  const float* x  = (const float*)d_in[0];
  const int* mask = (const int*)d_in[1];
  const float* Wq = (const float*)d_in[2];
  const float* bq = (const float*)d_in[3];
  const float* Wk = (const float*)d_in[4];
  const float* bk = (const float*)d_in[5];
  const float* Wv = (const float*)d_in[6];
  const float* bv = (const float*)d_in[7];
  const float* Wo = (const float*)d_in[8];
  const float* bo = (const float*)d_in[9];
  float* out = (float*)d_out;

  u16* ws   = (u16*)d_ws;
  u16* x_bf = ws;                          // [b*S+s][e]
  u16* w_t  = x_bf + (size_t)BSc*Ec;       // 4 transposed weight matrices [n][k]
  u16* q_bf = w_t  + (size_t)4*Ec*Ec;      // [bh][s][d], pre-scaled by 0.125*log2e
  u16* k_bf = q_bf + (size_t)BSc*Ec;       // [bh][s][d]
  u16* v_t  = k_bf + (size_t)BSc*Ec;       // [bh][d][s]
  u16* o_bf = v_t  + (size_t)BSc*Ec;       // [b*S+s][e]

  cvt_x_kernel<<<BSc*Ec/1024, 256, 0, stream>>>(x, x_bf, BSc*Ec);
  wt_kernel<<<dim3(32,32,4), 256, 0, stream>>>(Wq, Wk, Wv, Wo, w_t);

  const size_t WSZ = (size_t)Ec*Ec;
  gemm_qkv<<<dim3(24,64), 256, 0, stream>>>(x_bf, w_t, bq, bk, bv, q_bf, k_bf, v_t);

  attn_kernel<<<dim3(1024), 256, 0, stream>>>(q_bf, k_bf, v_t, mask, o_bf);

  gemm_out<<<dim3(8,64), 256, 0, stream>>>(o_bf, w_t+3*WSZ, bo, out);
}